// Round 6
// baseline (143.123 us; speedup 1.0000x reference)
//
#include <hip/hip_runtime.h>

// StyleConv3D implicit-GEMM on bf16 MFMA (gfx950).
// B=8, Cin=32, Cout=32, D=48, K=3, VALID -> Dout=46.
// R6: occupancy attack. Tile 6z x 4y x 50x (1216 sites), LDS 2x19KB=38.9KB
//     -> 4 blocks/CU = 32 waves/CU (was 2 blocks/16 waves at 64KB).
//     Compute core = R4 (distance-1 A prefetch, no setprio, no PREA).

typedef unsigned short u16;
typedef __bf16 bf16x8 __attribute__((ext_vector_type(8)));
typedef u16 u16x8 __attribute__((ext_vector_type(8)));
typedef float f32x4 __attribute__((ext_vector_type(4)));

#define CHUNKB   (110592 * 16)        // bytes per (b,c) chunk of xT
#define XT_BYTES (32u * CHUNKB)       // 56,623,104
#define WA_ELEMS (8 * 4 * 32 * 28 * 8)

__device__ __forceinline__ u16 f2bf(float f) {
    __bf16 h = (__bf16)f;
    return __builtin_bit_cast(u16, h);
}

__device__ __forceinline__ void dma16(const void* g, void* l) {
    __builtin_amdgcn_global_load_lds(
        (const __attribute__((address_space(1))) unsigned*)g,
        (__attribute__((address_space(3))) unsigned*)l, 16, 0, 0);
}

// ---------------- pre-pass: x f32 -> xT bf16 [bc][site][ci8] -------------
__global__ __launch_bounds__(256) void xpose_kernel(
    const float* __restrict__ x, u16* __restrict__ xT)
{
    int gid = blockIdx.x * 256 + threadIdx.x;    // 884,736 threads
    int quad = gid % 27648;
    int bc   = gid / 27648;                      // b*4 + c
    int site0 = quad * 4;
    const float* xp = x + (size_t)bc * 8 * 110592 + site0;
    float4 v[8];
#pragma unroll
    for (int j = 0; j < 8; ++j) v[j] = *(const float4*)(xp + (size_t)j * 110592);
    u16* op = xT + (size_t)gid * 32;
#pragma unroll
    for (int k = 0; k < 4; ++k) {
        u16x8 o;
#pragma unroll
        for (int j = 0; j < 8; ++j) o[j] = f2bf(((const float*)&v[j])[k]);
        *(u16x8*)(op + k * 8) = o;
    }
}

// ---------------- wnorm (main): wA[b][c4][cout][tap28][ci8] --------------
__global__ __launch_bounds__(64) void wnorm8_kernel(
    const float* __restrict__ s, const float* __restrict__ sw,
    const float* __restrict__ sb, const float* __restrict__ w,
    u16* __restrict__ wA)
{
    int bc = blockIdx.x;
    int b = bc >> 5, co = bc & 31;
    int lane = threadIdx.x;
    float s0 = s[2 * b], s1 = s[2 * b + 1];

    float sum = 0.f;
    for (int i = lane; i < 864; i += 64) {
        int ci = i / 27;
        float m = fmaf(s0, sw[2 * ci], fmaf(s1, sw[2 * ci + 1], sb[ci]));
        float v = w[co * 864 + i] * m;
        sum += v * v;
    }
#pragma unroll
    for (int off = 32; off; off >>= 1) sum += __shfl_xor(sum, off, 64);
    float rn = 1.0f / sqrtf(sum + 1e-8f);

    for (int i = lane; i < 864; i += 64) {
        int ci = i / 27, tap = i - ci * 27;
        float m = fmaf(s0, sw[2 * ci], fmaf(s1, sw[2 * ci + 1], sb[ci]));
        float v = w[co * 864 + i] * m * rn;
        int chunk = ci >> 3, ci8 = ci & 7;
        wA[(((b * 4 + chunk) * 32 + co) * 28 + tap) * 8 + ci8] = f2bf(v);
    }
    if (lane < 32) {
        int c = lane >> 3, ci8 = lane & 7;
        wA[(((b * 4 + c) * 32 + co) * 28 + 27) * 8 + ci8] = 0;
    }
}

// ---------------- conv (main): DMA-staged implicit GEMM ------------------
// Block (b, zt, yt): outputs z0..z0+3 (mask >=46), y0..y0+1, x 0..47
// (mask >=46). LDS tile: [z6][y4][x50] sites x 8ci bf16, site=z*200+y*50+x,
// padded to 1216 sites; 2 bufs x 19,456 B = 38,912 B -> 4 blocks/CU.
__global__ __launch_bounds__(512, 8) void conv_dma(
    const u16* __restrict__ xT, const u16* __restrict__ wA,
    const float* __restrict__ bias, float* __restrict__ out)
{
    __shared__ u16 sx[2][9728];   // 1216 sites x 8 ci

    int blk = blockIdx.x;
    int zt = blk % 12, yt = (blk / 12) % 23, b = blk / 276;
    int z0 = zt * 4, y0 = yt * 2;

    int t = threadIdx.x;
    int l = t & 63, w = t >> 6;
    int ln = l & 15;            // MFMA col (x within 16-tile) / A cout row
    int tq = l >> 4;            // k-octet: tap = 4s + tq
    int zw = w & 3, yp = w >> 2;   // wave -> (z row, y row)

    // ---- per-thread B-read base per k-step (bytes into a buf) ----
    int bbase[7];
#pragma unroll
    for (int s = 0; s < 7; ++s) {
        int tap = 4 * s + tq; if (tap > 26) tap = 26;   // pad tap: A is 0
        int dz = tap / 9, rr = tap - dz * 9;
        int dy = rr / 3, dx = rr - dy * 3;
        bbase[s] = ((zw + dz) * 200 + (yp + dy) * 50 + ln + dx) * 16;
    }
    int aoff = (ln * 28 + tq) * 16;   // bytes; +64/step, +7168 for half 1

    f32x4 acc[3][2];              // [x-tile][cout-half]
#pragma unroll
    for (int j = 0; j < 3; j++)
#pragma unroll
        for (int h = 0; h < 2; h++) acc[j][h] = (f32x4)0.f;

    const char* xc = (const char*)xT + (size_t)(b * 4) * CHUNKB;

#define ISSUE1(c, d, i, cond) if (cond) { \
    int sidx = t + (i) * 512; \
    int z = sidx / 200, r_ = sidx - z * 200; \
    int y = r_ / 50, x = r_ - y * 50; \
    long o = ((long)((z0 + z) * 48 + (y0 + y)) * 48 + x) * 16; \
    long mx = (long)CHUNKB - 16; \
    size_t go = (size_t)(o < mx ? o : mx); \
    dma16(xc + (size_t)(c) * CHUNKB + go, \
          (char*)&sx[d][0] + (size_t)((i) * 512 + w * 64) * 16); }

#define ISSUE(c, d) ISSUE1(c, d, 0, true) ISSUE1(c, d, 1, true) ISSUE1(c, d, 2, (w < 3))

#define COMPUTE(c, d) { \
    const char* wB = (const char*)(wA + (size_t)(b * 4 + (c)) * (32 * 28 * 8)); \
    const char* sb_ = (const char*)&sx[d][0]; \
    u16x8 A0 = *(const u16x8*)(wB + aoff); \
    u16x8 A1 = *(const u16x8*)(wB + aoff + 7168); \
    _Pragma("unroll") \
    for (int s = 0; s < 7; ++s) { \
        u16x8 nA0 = A0, nA1 = A1; \
        if (s < 6) { \
            nA0 = *(const u16x8*)(wB + aoff + (s + 1) * 64); \
            nA1 = *(const u16x8*)(wB + aoff + 7168 + (s + 1) * 64); \
        } \
        const char* p = sb_ + bbase[s]; \
        _Pragma("unroll") \
        for (int xt = 0; xt < 3; ++xt) { \
            bf16x8 Bf = *(const bf16x8*)(p + xt * 256); \
            acc[xt][0] = __builtin_amdgcn_mfma_f32_16x16x32_bf16( \
                __builtin_bit_cast(bf16x8, A0), Bf, acc[xt][0], 0, 0, 0); \
            acc[xt][1] = __builtin_amdgcn_mfma_f32_16x16x32_bf16( \
                __builtin_bit_cast(bf16x8, A1), Bf, acc[xt][1], 0, 0, 0); \
        } \
        A0 = nA0; A1 = nA1; \
    } }

    ISSUE(0, 0)
    __syncthreads();          // chunk 0 in LDS
    ISSUE(1, 1)
    COMPUTE(0, 0)
    __syncthreads();          // chunk 1 landed; buf0 free
    ISSUE(2, 0)
    COMPUTE(1, 1)
    __syncthreads();
    ISSUE(3, 1)
    COMPUTE(2, 0)
    __syncthreads();
    COMPUTE(3, 1)

    // ---- store: C layout col=lane&15 (x), row=(lane>>4)*4+reg (cout) ----
    int oz = z0 + zw;
    int oy = y0 + yp;
    if (oz < 46) {
#pragma unroll
        for (int xt = 0; xt < 3; ++xt) {
            int ox = xt * 16 + ln;
            if (ox >= 46) continue;
#pragma unroll
            for (int h = 0; h < 2; ++h) {
                f32x4 a = acc[xt][h];
#pragma unroll
                for (int r = 0; r < 4; ++r) {
                    int co = h * 16 + tq * 4 + r;
                    out[(size_t)(b * 32 + co) * 97336 + oz * 2116 + oy * 46 + ox]
                        = a[r] + bias[co];
                }
            }
        }
    }
#undef ISSUE
#undef ISSUE1
#undef COMPUTE
}

// ================= fallback path (R2, proven) ============================
__global__ __launch_bounds__(64) void wnorm16_kernel(
    const float* __restrict__ s, const float* __restrict__ sw,
    const float* __restrict__ sb, const float* __restrict__ w,
    u16* __restrict__ wA)          // [b][chunk2][cout][tap28][ci16]
{
    int bc = blockIdx.x;
    int b = bc >> 5, co = bc & 31;
    int lane = threadIdx.x;
    float s0 = s[2 * b], s1 = s[2 * b + 1];

    float sum = 0.f;
    for (int i = lane; i < 864; i += 64) {
        int ci = i / 27;
        float m = fmaf(s0, sw[2 * ci], fmaf(s1, sw[2 * ci + 1], sb[ci]));
        float v = w[co * 864 + i] * m;
        sum += v * v;
    }
#pragma unroll
    for (int off = 32; off; off >>= 1) sum += __shfl_xor(sum, off, 64);
    float rn = 1.0f / sqrtf(sum + 1e-8f);

    for (int i = lane; i < 864; i += 64) {
        int ci = i / 27, tap = i - ci * 27;
        float m = fmaf(s0, sw[2 * ci], fmaf(s1, sw[2 * ci + 1], sb[ci]));
        float v = w[co * 864 + i] * m * rn;
        int chunk = ci >> 4, ci16 = ci & 15;
        wA[(((b * 2 + chunk) * 32 + co) * 28 + tap) * 16 + ci16] = f2bf(v);
    }
    if (lane < 32) {
        int c = lane >> 4, ci16 = lane & 15;
        wA[(((b * 2 + c) * 32 + co) * 28 + 27) * 16 + ci16] = 0;
    }
}

__global__ __launch_bounds__(512) void conv_fallback(
    const float* __restrict__ xin, const u16* __restrict__ wA,
    const float* __restrict__ bias, float* __restrict__ out)
{
    __shared__ u16 sx[28800];

    int blk = blockIdx.x;
    int zt = blk % 12, yt = (blk / 12) % 12, b = blk / 144;
    int z0 = zt * 4, y0 = yt * 4;

    int t = threadIdx.x;
    int l = t & 63, w = t >> 6;
    int ln = l & 15, ch = (l >> 4) & 1, tp = l >> 5, rg = l >> 4;
    int zw = w & 3, yp = w >> 2;

    f32x4 acc[2][3][2];
#pragma unroll
    for (int i = 0; i < 2; i++)
#pragma unroll
        for (int j = 0; j < 3; j++)
#pragma unroll
            for (int h = 0; h < 2; h++) acc[i][j][h] = (f32x4)0.f;

    for (int chunk = 0; chunk < 2; ++chunk) {
        __syncthreads();
        for (int idx = t; idx < 3600; idx += 512) {
            int x = idx % 50;
            int r = idx / 50;
            int cg = r & 1; r >>= 1;
            int y = r % 6, z = r / 6;
            int gz = z0 + z, gy = y0 + y;
            bool inb = (x < 48) && (gy < 48) && (gz < 48);
            const float* xp = xin + (size_t)(b * 32 + chunk * 16 + cg * 8) * 110592
                              + gz * 2304 + gy * 48 + x;
            u16x8 v;
#pragma unroll
            for (int j = 0; j < 8; j++) {
                float f = inb ? xp[(size_t)j * 110592] : 0.f;
                v[j] = f2bf(f);
            }
            *(u16x8*)&sx[idx * 8] = v;
        }
        __syncthreads();

        const u16* wAc = wA + (b * 2 + chunk) * (32 * 28 * 16);
        int aoff = (ln * 28 + tp) * 16 + ch * 8;

#pragma unroll
        for (int s = 0; s < 14; ++s) {
            int tapA = 2 * s + tp;
            bf16x8 A0 = __builtin_bit_cast(bf16x8, *(const u16x8*)(wAc + aoff + s * 32));
            bf16x8 A1 = __builtin_bit_cast(bf16x8, *(const u16x8*)(wAc + aoff + 16 * 28 * 16 + s * 32));
            int tapB = tapA > 26 ? 26 : tapA;
            int dz = tapB / 9;
            int rr = tapB - dz * 9;
            int dy = rr / 3;
            int dx = rr - dy * 3;
            int zr = zw + dz;
#pragma unroll
            for (int yr = 0; yr < 2; ++yr) {
                int yy = 2 * yp + yr + dy;
                int eb = (((zr * 6 + yy) * 2 + ch) * 50 + ln + dx) * 8;
#pragma unroll
                for (int xt = 0; xt < 3; ++xt) {
                    bf16x8 Bf = __builtin_bit_cast(bf16x8, *(const u16x8*)&sx[eb + xt * 128]);
                    acc[yr][xt][0] = __builtin_amdgcn_mfma_f32_16x16x32_bf16(A0, Bf, acc[yr][xt][0], 0, 0, 0);
                    acc[yr][xt][1] = __builtin_amdgcn_mfma_f32_16x16x32_bf16(A1, Bf, acc[yr][xt][1], 0, 0, 0);
                }
            }
        }
    }

    int oz = z0 + zw;
    if (oz < 46) {
#pragma unroll
        for (int yr = 0; yr < 2; ++yr) {
            int oy = y0 + 2 * yp + yr;
            if (oy >= 46) continue;
#pragma unroll
            for (int xt = 0; xt < 3; ++xt) {
                int ox = xt * 16 + ln;
                if (ox >= 46) continue;
#pragma unroll
                for (int h = 0; h < 2; ++h) {
                    f32x4 a = acc[yr][xt][h];
#pragma unroll
                    for (int r = 0; r < 4; ++r) {
                        int co = h * 16 + rg * 4 + r;
                        out[(size_t)(b * 32 + co) * 97336 + oz * 2116 + oy * 46 + ox]
                            = a[r] + bias[co];
                    }
                }
            }
        }
    }
}

extern "C" void kernel_launch(void* const* d_in, const int* in_sizes, int n_in,
                              void* d_out, int out_size, void* d_ws, size_t ws_size,
                              hipStream_t stream) {
    const float* x    = (const float*)d_in[0];
    const float* s    = (const float*)d_in[1];
    const float* sw   = (const float*)d_in[2];
    const float* sb   = (const float*)d_in[3];
    const float* wgt  = (const float*)d_in[4];
    const float* bias = (const float*)d_in[5];
    float* out = (float*)d_out;

    const size_t need = (size_t)XT_BYTES + WA_ELEMS * sizeof(u16);
    if (ws_size >= need) {
        u16* xT = (u16*)d_ws;
        u16* wA = (u16*)((char*)d_ws + XT_BYTES);
        hipLaunchKernelGGL(xpose_kernel, dim3(3456), dim3(256), 0, stream, x, xT);
        hipLaunchKernelGGL(wnorm8_kernel, dim3(256), dim3(64), 0, stream,
                           s, sw, sb, wgt, wA);
        hipLaunchKernelGGL(conv_dma, dim3(12 * 23 * 8), dim3(512), 0, stream,
                           xT, wA, bias, out);
    } else {
        u16* wA = (u16*)d_ws;
        hipLaunchKernelGGL(wnorm16_kernel, dim3(256), dim3(64), 0, stream,
                           s, sw, sb, wgt, wA);
        hipLaunchKernelGGL(conv_fallback, dim3(12 * 12 * 8), dim3(512), 0, stream,
                           x, wA, bias, out);
    }
}

// Round 7
// 105.468 us; speedup vs baseline: 1.3570x; 1.3570x over previous
//
#include <hip/hip_runtime.h>

// StyleConv3D implicit-GEMM on bf16 MFMA (gfx950).
// B=8, Cin=32, Cout=32, D=48, K=3, VALID -> Dout=46.
// R7: R4 geometry (6x6x50 tile, 2x32KB dbuf, 2 blocks/CU) +
//     explicit double-buffered B-frag/A-frag registers (dist-1 software
//     pipeline with named regs, literal step indices) + XCD swizzle.
//     R5 lesson: unfenced preloads get sunk at VGPR=64; force liveness
//     by structuring the dataflow, budget ~126 regs under (512,4)'s 128.

typedef unsigned short u16;
typedef __bf16 bf16x8 __attribute__((ext_vector_type(8)));
typedef u16 u16x8 __attribute__((ext_vector_type(8)));
typedef float f32x4 __attribute__((ext_vector_type(4)));

#define CHUNKB   (110592 * 16)        // bytes per (b,c) chunk of xT
#define XT_BYTES (32u * CHUNKB)       // 56,623,104
#define WA_ELEMS (8 * 4 * 32 * 28 * 8)

__device__ __forceinline__ u16 f2bf(float f) {
    __bf16 h = (__bf16)f;
    return __builtin_bit_cast(u16, h);
}

__device__ __forceinline__ void dma16(const void* g, void* l) {
    __builtin_amdgcn_global_load_lds(
        (const __attribute__((address_space(1))) unsigned*)g,
        (__attribute__((address_space(3))) unsigned*)l, 16, 0, 0);
}

// ---------------- pre-pass: x f32 -> xT bf16 [bc][site][ci8] -------------
__global__ __launch_bounds__(256) void xpose_kernel(
    const float* __restrict__ x, u16* __restrict__ xT)
{
    int gid = blockIdx.x * 256 + threadIdx.x;    // 884,736 threads
    int quad = gid % 27648;
    int bc   = gid / 27648;                      // b*4 + c
    int site0 = quad * 4;
    const float* xp = x + (size_t)bc * 8 * 110592 + site0;
    float4 v[8];
#pragma unroll
    for (int j = 0; j < 8; ++j) v[j] = *(const float4*)(xp + (size_t)j * 110592);
    u16* op = xT + (size_t)gid * 32;
#pragma unroll
    for (int k = 0; k < 4; ++k) {
        u16x8 o;
#pragma unroll
        for (int j = 0; j < 8; ++j) o[j] = f2bf(((const float*)&v[j])[k]);
        *(u16x8*)(op + k * 8) = o;
    }
}

// ---------------- wnorm (main): wA[b][c4][cout][tap28][ci8] --------------
__global__ __launch_bounds__(64) void wnorm8_kernel(
    const float* __restrict__ s, const float* __restrict__ sw,
    const float* __restrict__ sb, const float* __restrict__ w,
    u16* __restrict__ wA)
{
    int bc = blockIdx.x;
    int b = bc >> 5, co = bc & 31;
    int lane = threadIdx.x;
    float s0 = s[2 * b], s1 = s[2 * b + 1];

    float sum = 0.f;
    for (int i = lane; i < 864; i += 64) {
        int ci = i / 27;
        float m = fmaf(s0, sw[2 * ci], fmaf(s1, sw[2 * ci + 1], sb[ci]));
        float v = w[co * 864 + i] * m;
        sum += v * v;
    }
#pragma unroll
    for (int off = 32; off; off >>= 1) sum += __shfl_xor(sum, off, 64);
    float rn = 1.0f / sqrtf(sum + 1e-8f);

    for (int i = lane; i < 864; i += 64) {
        int ci = i / 27, tap = i - ci * 27;
        float m = fmaf(s0, sw[2 * ci], fmaf(s1, sw[2 * ci + 1], sb[ci]));
        float v = w[co * 864 + i] * m * rn;
        int chunk = ci >> 3, ci8 = ci & 7;
        wA[(((b * 4 + chunk) * 32 + co) * 28 + tap) * 8 + ci8] = f2bf(v);
    }
    if (lane < 32) {
        int c = lane >> 3, ci8 = lane & 7;
        wA[(((b * 4 + c) * 32 + co) * 28 + 27) * 8 + ci8] = 0;
    }
}

// ---------------- conv (main): DMA-staged implicit GEMM ------------------
__global__ __launch_bounds__(512, 4) void conv_dma(
    const u16* __restrict__ xT, const u16* __restrict__ wA,
    const float* __restrict__ bias, float* __restrict__ out)
{
    __shared__ u16 sx[2][16384];

    // XCD-aware bijective swizzle: 1152 = 8 XCD * 144; each XCD gets one b.
    int orig = blockIdx.x;
    int blk = (orig & 7) * 144 + (orig >> 3);

    int zt = blk % 12, yt = (blk / 12) % 12, b = blk / 144;
    int z0 = zt * 4, y0 = yt * 4;

    int t = threadIdx.x;
    int l = t & 63, w = t >> 6;
    int ln = l & 15;            // MFMA col (x within 16-tile) / A cout row
    int tq = l >> 4;            // k-octet: tap = 4s + tq
    int zw = w & 3, yp = w >> 2;

    // ---- per-thread B-read base per k-step (bytes into a buf) ----
    int bbase[7];
#pragma unroll
    for (int s = 0; s < 7; ++s) {
        int tap = 4 * s + tq; if (tap > 26) tap = 26;   // pad tap: A is 0
        int dz = tap / 9, rr = tap - dz * 9;
        int dy = rr / 3, dx = rr - dy * 3;
        bbase[s] = ((zw + dz) * 300 + (2 * yp + dy) * 50 + ln + dx) * 16;
    }
    int aoff = (ln * 28 + tq) * 16;   // bytes; +64/step, +7168 for half 1

    f32x4 acc[2][3][2];
#pragma unroll
    for (int i = 0; i < 2; i++)
#pragma unroll
        for (int j = 0; j < 3; j++)
#pragma unroll
            for (int h = 0; h < 2; h++) acc[i][j][h] = (f32x4)0.f;

    const char* xc = (const char*)xT + (size_t)(b * 4) * CHUNKB;

#define ISSUE(c, d) { \
    _Pragma("unroll") \
    for (int i = 0; i < 4; ++i) { \
        int sidx = t + i * 512; \
        int z = sidx / 300, r_ = sidx - z * 300; \
        int y = r_ / 50, x = r_ - y * 50; \
        long o = ((long)((z0 + z) * 48 + (y0 + y)) * 48 + x) * 16; \
        long mx = (long)CHUNKB - 16; \
        size_t go = (size_t)(o < mx ? o : mx); \
        dma16(xc + (size_t)(c) * CHUNKB + go, \
              (char*)&sx[d][0] + (size_t)(i * 512 + w * 64) * 16); } }

    // ---- software-pipelined k-loop: named dual register sets -----------
    // set a / set b alternate; all step indices are literals.
#define BREAD(p0, p1, p2, p3, p4, p5, sidx) { \
    const char* p = sb_ + bbase[sidx]; \
    p0 = *(const u16x8*)(p); \
    p1 = *(const u16x8*)(p + 256); \
    p2 = *(const u16x8*)(p + 512); \
    p3 = *(const u16x8*)(p + 800); \
    p4 = *(const u16x8*)(p + 800 + 256); \
    p5 = *(const u16x8*)(p + 800 + 512); }

#define AREAD(A0, A1, sidx) { \
    A0 = *(const u16x8*)(wB + aoff + (sidx) * 64); \
    A1 = *(const u16x8*)(wB + aoff + 7168 + (sidx) * 64); }

#define MFMA6(A0, A1, f0, f1, f2, f3, f4, f5) { \
    acc[0][0][0] = __builtin_amdgcn_mfma_f32_16x16x32_bf16(__builtin_bit_cast(bf16x8, A0), __builtin_bit_cast(bf16x8, f0), acc[0][0][0], 0, 0, 0); \
    acc[0][0][1] = __builtin_amdgcn_mfma_f32_16x16x32_bf16(__builtin_bit_cast(bf16x8, A1), __builtin_bit_cast(bf16x8, f0), acc[0][0][1], 0, 0, 0); \
    acc[0][1][0] = __builtin_amdgcn_mfma_f32_16x16x32_bf16(__builtin_bit_cast(bf16x8, A0), __builtin_bit_cast(bf16x8, f1), acc[0][1][0], 0, 0, 0); \
    acc[0][1][1] = __builtin_amdgcn_mfma_f32_16x16x32_bf16(__builtin_bit_cast(bf16x8, A1), __builtin_bit_cast(bf16x8, f1), acc[0][1][1], 0, 0, 0); \
    acc[0][2][0] = __builtin_amdgcn_mfma_f32_16x16x32_bf16(__builtin_bit_cast(bf16x8, A0), __builtin_bit_cast(bf16x8, f2), acc[0][2][0], 0, 0, 0); \
    acc[0][2][1] = __builtin_amdgcn_mfma_f32_16x16x32_bf16(__builtin_bit_cast(bf16x8, A1), __builtin_bit_cast(bf16x8, f2), acc[0][2][1], 0, 0, 0); \
    acc[1][0][0] = __builtin_amdgcn_mfma_f32_16x16x32_bf16(__builtin_bit_cast(bf16x8, A0), __builtin_bit_cast(bf16x8, f3), acc[1][0][0], 0, 0, 0); \
    acc[1][0][1] = __builtin_amdgcn_mfma_f32_16x16x32_bf16(__builtin_bit_cast(bf16x8, A1), __builtin_bit_cast(bf16x8, f3), acc[1][0][1], 0, 0, 0); \
    acc[1][1][0] = __builtin_amdgcn_mfma_f32_16x16x32_bf16(__builtin_bit_cast(bf16x8, A0), __builtin_bit_cast(bf16x8, f4), acc[1][1][0], 0, 0, 0); \
    acc[1][1][1] = __builtin_amdgcn_mfma_f32_16x16x32_bf16(__builtin_bit_cast(bf16x8, A1), __builtin_bit_cast(bf16x8, f4), acc[1][1][1], 0, 0, 0); \
    acc[1][2][0] = __builtin_amdgcn_mfma_f32_16x16x32_bf16(__builtin_bit_cast(bf16x8, A0), __builtin_bit_cast(bf16x8, f5), acc[1][2][0], 0, 0, 0); \
    acc[1][2][1] = __builtin_amdgcn_mfma_f32_16x16x32_bf16(__builtin_bit_cast(bf16x8, A1), __builtin_bit_cast(bf16x8, f5), acc[1][2][1], 0, 0, 0); }

#define COMPUTE(c, d) { \
    const char* wB = (const char*)(wA + (size_t)(b * 4 + (c)) * (32 * 28 * 8)); \
    const char* sb_ = (const char*)&sx[d][0]; \
    u16x8 fa0, fa1, fa2, fa3, fa4, fa5, fb0, fb1, fb2, fb3, fb4, fb5; \
    u16x8 Aa0, Aa1, Ab0, Ab1; \
    BREAD(fa0, fa1, fa2, fa3, fa4, fa5, 0) \
    AREAD(Aa0, Aa1, 0) \
    /* s=0 */ BREAD(fb0, fb1, fb2, fb3, fb4, fb5, 1) AREAD(Ab0, Ab1, 1) \
              MFMA6(Aa0, Aa1, fa0, fa1, fa2, fa3, fa4, fa5) \
    /* s=1 */ BREAD(fa0, fa1, fa2, fa3, fa4, fa5, 2) AREAD(Aa0, Aa1, 2) \
              MFMA6(Ab0, Ab1, fb0, fb1, fb2, fb3, fb4, fb5) \
    /* s=2 */ BREAD(fb0, fb1, fb2, fb3, fb4, fb5, 3) AREAD(Ab0, Ab1, 3) \
              MFMA6(Aa0, Aa1, fa0, fa1, fa2, fa3, fa4, fa5) \
    /* s=3 */ BREAD(fa0, fa1, fa2, fa3, fa4, fa5, 4) AREAD(Aa0, Aa1, 4) \
              MFMA6(Ab0, Ab1, fb0, fb1, fb2, fb3, fb4, fb5) \
    /* s=4 */ BREAD(fb0, fb1, fb2, fb3, fb4, fb5, 5) AREAD(Ab0, Ab1, 5) \
              MFMA6(Aa0, Aa1, fa0, fa1, fa2, fa3, fa4, fa5) \
    /* s=5 */ BREAD(fa0, fa1, fa2, fa3, fa4, fa5, 6) AREAD(Aa0, Aa1, 6) \
              MFMA6(Ab0, Ab1, fb0, fb1, fb2, fb3, fb4, fb5) \
    /* s=6 */ MFMA6(Aa0, Aa1, fa0, fa1, fa2, fa3, fa4, fa5) }

    ISSUE(0, 0)
    __syncthreads();          // chunk 0 in LDS
    ISSUE(1, 1)
    COMPUTE(0, 0)
    __syncthreads();          // chunk 1 landed; buf0 free
    ISSUE(2, 0)
    COMPUTE(1, 1)
    __syncthreads();
    ISSUE(3, 1)
    COMPUTE(2, 0)
    __syncthreads();
    COMPUTE(3, 1)

    // ---- store: C layout col=lane&15 (x), row=(lane>>4)*4+reg (cout) ----
    int oz = z0 + zw;
    if (oz < 46) {
#pragma unroll
        for (int yr = 0; yr < 2; ++yr) {
            int oy = y0 + 2 * yp + yr;
            if (oy >= 46) continue;
#pragma unroll
            for (int xt = 0; xt < 3; ++xt) {
                int ox = xt * 16 + ln;
                if (ox >= 46) continue;
#pragma unroll
                for (int h = 0; h < 2; ++h) {
                    f32x4 a = acc[yr][xt][h];
#pragma unroll
                    for (int r = 0; r < 4; ++r) {
                        int co = h * 16 + tq * 4 + r;
                        out[(size_t)(b * 32 + co) * 97336 + oz * 2116 + oy * 46 + ox]
                            = a[r] + bias[co];
                    }
                }
            }
        }
    }
#undef ISSUE
#undef BREAD
#undef AREAD
#undef MFMA6
#undef COMPUTE
}

// ================= fallback path (R2, proven) ============================
__global__ __launch_bounds__(64) void wnorm16_kernel(
    const float* __restrict__ s, const float* __restrict__ sw,
    const float* __restrict__ sb, const float* __restrict__ w,
    u16* __restrict__ wA)          // [b][chunk2][cout][tap28][ci16]
{
    int bc = blockIdx.x;
    int b = bc >> 5, co = bc & 31;
    int lane = threadIdx.x;
    float s0 = s[2 * b], s1 = s[2 * b + 1];

    float sum = 0.f;
    for (int i = lane; i < 864; i += 64) {
        int ci = i / 27;
        float m = fmaf(s0, sw[2 * ci], fmaf(s1, sw[2 * ci + 1], sb[ci]));
        float v = w[co * 864 + i] * m;
        sum += v * v;
    }
#pragma unroll
    for (int off = 32; off; off >>= 1) sum += __shfl_xor(sum, off, 64);
    float rn = 1.0f / sqrtf(sum + 1e-8f);

    for (int i = lane; i < 864; i += 64) {
        int ci = i / 27, tap = i - ci * 27;
        float m = fmaf(s0, sw[2 * ci], fmaf(s1, sw[2 * ci + 1], sb[ci]));
        float v = w[co * 864 + i] * m * rn;
        int chunk = ci >> 4, ci16 = ci & 15;
        wA[(((b * 2 + chunk) * 32 + co) * 28 + tap) * 16 + ci16] = f2bf(v);
    }
    if (lane < 32) {
        int c = lane >> 4, ci16 = lane & 15;
        wA[(((b * 2 + c) * 32 + co) * 28 + 27) * 16 + ci16] = 0;
    }
}

__global__ __launch_bounds__(512) void conv_fallback(
    const float* __restrict__ xin, const u16* __restrict__ wA,
    const float* __restrict__ bias, float* __restrict__ out)
{
    __shared__ u16 sx[28800];

    int blk = blockIdx.x;
    int zt = blk % 12, yt = (blk / 12) % 12, b = blk / 144;
    int z0 = zt * 4, y0 = yt * 4;

    int t = threadIdx.x;
    int l = t & 63, w = t >> 6;
    int ln = l & 15, ch = (l >> 4) & 1, tp = l >> 5, rg = l >> 4;
    int zw = w & 3, yp = w >> 2;

    f32x4 acc[2][3][2];
#pragma unroll
    for (int i = 0; i < 2; i++)
#pragma unroll
        for (int j = 0; j < 3; j++)
#pragma unroll
            for (int h = 0; h < 2; h++) acc[i][j][h] = (f32x4)0.f;

    for (int chunk = 0; chunk < 2; ++chunk) {
        __syncthreads();
        for (int idx = t; idx < 3600; idx += 512) {
            int x = idx % 50;
            int r = idx / 50;
            int cg = r & 1; r >>= 1;
            int y = r % 6, z = r / 6;
            int gz = z0 + z, gy = y0 + y;
            bool inb = (x < 48) && (gy < 48) && (gz < 48);
            const float* xp = xin + (size_t)(b * 32 + chunk * 16 + cg * 8) * 110592
                              + gz * 2304 + gy * 48 + x;
            u16x8 v;
#pragma unroll
            for (int j = 0; j < 8; j++) {
                float f = inb ? xp[(size_t)j * 110592] : 0.f;
                v[j] = f2bf(f);
            }
            *(u16x8*)&sx[idx * 8] = v;
        }
        __syncthreads();

        const u16* wAc = wA + (b * 2 + chunk) * (32 * 28 * 16);
        int aoff = (ln * 28 + tp) * 16 + ch * 8;

#pragma unroll
        for (int s = 0; s < 14; ++s) {
            int tapA = 2 * s + tp;
            bf16x8 A0 = __builtin_bit_cast(bf16x8, *(const u16x8*)(wAc + aoff + s * 32));
            bf16x8 A1 = __builtin_bit_cast(bf16x8, *(const u16x8*)(wAc + aoff + 16 * 28 * 16 + s * 32));
            int tapB = tapA > 26 ? 26 : tapA;
            int dz = tapB / 9;
            int rr = tapB - dz * 9;
            int dy = rr / 3;
            int dx = rr - dy * 3;
            int zr = zw + dz;
#pragma unroll
            for (int yr = 0; yr < 2; ++yr) {
                int yy = 2 * yp + yr + dy;
                int eb = (((zr * 6 + yy) * 2 + ch) * 50 + ln + dx) * 8;
#pragma unroll
                for (int xt = 0; xt < 3; ++xt) {
                    bf16x8 Bf = __builtin_bit_cast(bf16x8, *(const u16x8*)&sx[eb + xt * 128]);
                    acc[yr][xt][0] = __builtin_amdgcn_mfma_f32_16x16x32_bf16(A0, Bf, acc[yr][xt][0], 0, 0, 0);
                    acc[yr][xt][1] = __builtin_amdgcn_mfma_f32_16x16x32_bf16(A1, Bf, acc[yr][xt][1], 0, 0, 0);
                }
            }
        }
    }

    int oz = z0 + zw;
    if (oz < 46) {
#pragma unroll
        for (int yr = 0; yr < 2; ++yr) {
            int oy = y0 + 2 * yp + yr;
            if (oy >= 46) continue;
#pragma unroll
            for (int xt = 0; xt < 3; ++xt) {
                int ox = xt * 16 + ln;
                if (ox >= 46) continue;
#pragma unroll
                for (int h = 0; h < 2; ++h) {
                    f32x4 a = acc[yr][xt][h];
#pragma unroll
                    for (int r = 0; r < 4; ++r) {
                        int co = h * 16 + rg * 4 + r;
                        out[(size_t)(b * 32 + co) * 97336 + oz * 2116 + oy * 46 + ox]
                            = a[r] + bias[co];
                    }
                }
            }
        }
    }
}

extern "C" void kernel_launch(void* const* d_in, const int* in_sizes, int n_in,
                              void* d_out, int out_size, void* d_ws, size_t ws_size,
                              hipStream_t stream) {
    const float* x    = (const float*)d_in[0];
    const float* s    = (const float*)d_in[1];
    const float* sw   = (const float*)d_in[2];
    const float* sb   = (const float*)d_in[3];
    const float* wgt  = (const float*)d_in[4];
    const float* bias = (const float*)d_in[5];
    float* out = (float*)d_out;

    const size_t need = (size_t)XT_BYTES + WA_ELEMS * sizeof(u16);
    if (ws_size >= need) {
        u16* xT = (u16*)d_ws;
        u16* wA = (u16*)((char*)d_ws + XT_BYTES);
        hipLaunchKernelGGL(xpose_kernel, dim3(3456), dim3(256), 0, stream, x, xT);
        hipLaunchKernelGGL(wnorm8_kernel, dim3(256), dim3(64), 0, stream,
                           s, sw, sb, wgt, wA);
        hipLaunchKernelGGL(conv_dma, dim3(12 * 12 * 8), dim3(512), 0, stream,
                           xT, wA, bias, out);
    } else {
        u16* wA = (u16*)d_ws;
        hipLaunchKernelGGL(wnorm16_kernel, dim3(256), dim3(64), 0, stream,
                           s, sw, sb, wgt, wA);
        hipLaunchKernelGGL(conv_fallback, dim3(12 * 12 * 8), dim3(512), 0, stream,
                           x, wA, bias, out);
    }
}

// Round 8
// 102.999 us; speedup vs baseline: 1.3896x; 1.0240x over previous
//
#include <hip/hip_runtime.h>

// StyleConv3D implicit-GEMM on bf16 MFMA (gfx950).
// B=8, Cin=32, Cout=32, D=48, K=3, VALID -> Dout=46.
// R8: R7 base (R4 geometry + XCD swizzle) + per-chunk A-fragment batch
//     hoist pinned by sched_barrier(0). A batch issued BEFORE ISSUE(c+1)
//     so A-waits (oldest vmcnt) never drain the staging DMAs.
//     R5/R7 lesson: plain named vars get re-sunk (VGPR stayed 56);
//     sched_barrier(0) blocks both MachineSink and the scheduler without
//     forcing an early s_waitcnt (unlike an asm-use pin).

typedef unsigned short u16;
typedef __bf16 bf16x8 __attribute__((ext_vector_type(8)));
typedef u16 u16x8 __attribute__((ext_vector_type(8)));
typedef float f32x4 __attribute__((ext_vector_type(4)));

#define CHUNKB   (110592 * 16)        // bytes per (b,c) chunk of xT
#define XT_BYTES (32u * CHUNKB)       // 56,623,104
#define WA_ELEMS (8 * 4 * 32 * 28 * 8)

__device__ __forceinline__ u16 f2bf(float f) {
    __bf16 h = (__bf16)f;
    return __builtin_bit_cast(u16, h);
}

__device__ __forceinline__ void dma16(const void* g, void* l) {
    __builtin_amdgcn_global_load_lds(
        (const __attribute__((address_space(1))) unsigned*)g,
        (__attribute__((address_space(3))) unsigned*)l, 16, 0, 0);
}

// ---------------- pre-pass: x f32 -> xT bf16 [bc][site][ci8] -------------
__global__ __launch_bounds__(256) void xpose_kernel(
    const float* __restrict__ x, u16* __restrict__ xT)
{
    int gid = blockIdx.x * 256 + threadIdx.x;    // 884,736 threads
    int quad = gid % 27648;
    int bc   = gid / 27648;                      // b*4 + c
    int site0 = quad * 4;
    const float* xp = x + (size_t)bc * 8 * 110592 + site0;
    float4 v[8];
#pragma unroll
    for (int j = 0; j < 8; ++j) v[j] = *(const float4*)(xp + (size_t)j * 110592);
    u16* op = xT + (size_t)gid * 32;
#pragma unroll
    for (int k = 0; k < 4; ++k) {
        u16x8 o;
#pragma unroll
        for (int j = 0; j < 8; ++j) o[j] = f2bf(((const float*)&v[j])[k]);
        *(u16x8*)(op + k * 8) = o;
    }
}

// ---------------- wnorm (main): wA[b][c4][cout][tap28][ci8] --------------
__global__ __launch_bounds__(64) void wnorm8_kernel(
    const float* __restrict__ s, const float* __restrict__ sw,
    const float* __restrict__ sb, const float* __restrict__ w,
    u16* __restrict__ wA)
{
    int bc = blockIdx.x;
    int b = bc >> 5, co = bc & 31;
    int lane = threadIdx.x;
    float s0 = s[2 * b], s1 = s[2 * b + 1];

    float sum = 0.f;
    for (int i = lane; i < 864; i += 64) {
        int ci = i / 27;
        float m = fmaf(s0, sw[2 * ci], fmaf(s1, sw[2 * ci + 1], sb[ci]));
        float v = w[co * 864 + i] * m;
        sum += v * v;
    }
#pragma unroll
    for (int off = 32; off; off >>= 1) sum += __shfl_xor(sum, off, 64);
    float rn = 1.0f / sqrtf(sum + 1e-8f);

    for (int i = lane; i < 864; i += 64) {
        int ci = i / 27, tap = i - ci * 27;
        float m = fmaf(s0, sw[2 * ci], fmaf(s1, sw[2 * ci + 1], sb[ci]));
        float v = w[co * 864 + i] * m * rn;
        int chunk = ci >> 3, ci8 = ci & 7;
        wA[(((b * 4 + chunk) * 32 + co) * 28 + tap) * 8 + ci8] = f2bf(v);
    }
    if (lane < 32) {
        int c = lane >> 3, ci8 = lane & 7;
        wA[(((b * 4 + c) * 32 + co) * 28 + 27) * 8 + ci8] = 0;
    }
}

// ---------------- conv (main): DMA-staged implicit GEMM ------------------
__global__ __launch_bounds__(512, 4) void conv_dma(
    const u16* __restrict__ xT, const u16* __restrict__ wA,
    const float* __restrict__ bias, float* __restrict__ out)
{
    __shared__ u16 sx[2][16384];

    // XCD-aware bijective swizzle: 1152 = 8 XCD * 144; each XCD gets one b.
    int orig = blockIdx.x;
    int blk = (orig & 7) * 144 + (orig >> 3);

    int zt = blk % 12, yt = (blk / 12) % 12, b = blk / 144;
    int z0 = zt * 4, y0 = yt * 4;

    int t = threadIdx.x;
    int l = t & 63, w = t >> 6;
    int ln = l & 15;            // MFMA col (x within 16-tile) / A cout row
    int tq = l >> 4;            // k-octet: tap = 4s + tq
    int zw = w & 3, yp = w >> 2;

    // ---- per-thread B-read base per k-step (bytes into a buf) ----
    int bbase[7];
#pragma unroll
    for (int s = 0; s < 7; ++s) {
        int tap = 4 * s + tq; if (tap > 26) tap = 26;   // pad tap: A is 0
        int dz = tap / 9, rr = tap - dz * 9;
        int dy = rr / 3, dx = rr - dy * 3;
        bbase[s] = ((zw + dz) * 300 + (2 * yp + dy) * 50 + ln + dx) * 16;
    }
    int aoff = (ln * 28 + tq) * 16;   // bytes; +64/step, +7168 for half 1

    f32x4 acc[2][3][2];
#pragma unroll
    for (int i = 0; i < 2; i++)
#pragma unroll
        for (int j = 0; j < 3; j++)
#pragma unroll
            for (int h = 0; h < 2; h++) acc[i][j][h] = (f32x4)0.f;

    const char* xc = (const char*)xT + (size_t)(b * 4) * CHUNKB;

#define ISSUE(c, d) { \
    _Pragma("unroll") \
    for (int i = 0; i < 4; ++i) { \
        int sidx = t + i * 512; \
        int z = sidx / 300, r_ = sidx - z * 300; \
        int y = r_ / 50, x = r_ - y * 50; \
        long o = ((long)((z0 + z) * 48 + (y0 + y)) * 48 + x) * 16; \
        long mx = (long)CHUNKB - 16; \
        size_t go = (size_t)(o < mx ? o : mx); \
        dma16(xc + (size_t)(c) * CHUNKB + go, \
              (char*)&sx[d][0] + (size_t)(i * 512 + w * 64) * 16); } }

#define MFMA6(A0, A1, f0, f1, f2, f3, f4, f5) { \
    acc[0][0][0] = __builtin_amdgcn_mfma_f32_16x16x32_bf16(__builtin_bit_cast(bf16x8, A0), __builtin_bit_cast(bf16x8, f0), acc[0][0][0], 0, 0, 0); \
    acc[0][0][1] = __builtin_amdgcn_mfma_f32_16x16x32_bf16(__builtin_bit_cast(bf16x8, A1), __builtin_bit_cast(bf16x8, f0), acc[0][0][1], 0, 0, 0); \
    acc[0][1][0] = __builtin_amdgcn_mfma_f32_16x16x32_bf16(__builtin_bit_cast(bf16x8, A0), __builtin_bit_cast(bf16x8, f1), acc[0][1][0], 0, 0, 0); \
    acc[0][1][1] = __builtin_amdgcn_mfma_f32_16x16x32_bf16(__builtin_bit_cast(bf16x8, A1), __builtin_bit_cast(bf16x8, f1), acc[0][1][1], 0, 0, 0); \
    acc[0][2][0] = __builtin_amdgcn_mfma_f32_16x16x32_bf16(__builtin_bit_cast(bf16x8, A0), __builtin_bit_cast(bf16x8, f2), acc[0][2][0], 0, 0, 0); \
    acc[0][2][1] = __builtin_amdgcn_mfma_f32_16x16x32_bf16(__builtin_bit_cast(bf16x8, A1), __builtin_bit_cast(bf16x8, f2), acc[0][2][1], 0, 0, 0); \
    acc[1][0][0] = __builtin_amdgcn_mfma_f32_16x16x32_bf16(__builtin_bit_cast(bf16x8, A0), __builtin_bit_cast(bf16x8, f3), acc[1][0][0], 0, 0, 0); \
    acc[1][0][1] = __builtin_amdgcn_mfma_f32_16x16x32_bf16(__builtin_bit_cast(bf16x8, A1), __builtin_bit_cast(bf16x8, f3), acc[1][0][1], 0, 0, 0); \
    acc[1][1][0] = __builtin_amdgcn_mfma_f32_16x16x32_bf16(__builtin_bit_cast(bf16x8, A0), __builtin_bit_cast(bf16x8, f4), acc[1][1][0], 0, 0, 0); \
    acc[1][1][1] = __builtin_amdgcn_mfma_f32_16x16x32_bf16(__builtin_bit_cast(bf16x8, A1), __builtin_bit_cast(bf16x8, f4), acc[1][1][1], 0, 0, 0); \
    acc[1][2][0] = __builtin_amdgcn_mfma_f32_16x16x32_bf16(__builtin_bit_cast(bf16x8, A0), __builtin_bit_cast(bf16x8, f5), acc[1][2][0], 0, 0, 0); \
    acc[1][2][1] = __builtin_amdgcn_mfma_f32_16x16x32_bf16(__builtin_bit_cast(bf16x8, A1), __builtin_bit_cast(bf16x8, f5), acc[1][2][1], 0, 0, 0); }

#define STEP(sidx, A0, A1) { \
    const char* p = sb_ + bbase[sidx]; \
    u16x8 f0 = *(const u16x8*)(p); \
    u16x8 f1 = *(const u16x8*)(p + 256); \
    u16x8 f2 = *(const u16x8*)(p + 512); \
    u16x8 f3 = *(const u16x8*)(p + 800); \
    u16x8 f4 = *(const u16x8*)(p + 800 + 256); \
    u16x8 f5 = *(const u16x8*)(p + 800 + 512); \
    MFMA6(A0, A1, f0, f1, f2, f3, f4, f5) }

#define ALOADP(A0, A1, sidx) \
    A0 = *(const u16x8*)(wB + aoff + (sidx) * 64); \
    A1 = *(const u16x8*)(wB + aoff + 7168 + (sidx) * 64);

    // Per chunk: A-batch1 (steps 0-3) BEFORE ISSUE -> A = oldest vmcnt items;
    // sched_barrier pins the batch (no forced wait, unlike an asm-use pin).
#define COMPUTE(c, d, DOISS, cn, dn) { \
    const char* wB = (const char*)(wA + (size_t)(b * 4 + (c)) * (32 * 28 * 8)); \
    const char* sb_ = (const char*)&sx[d][0]; \
    u16x8 A00, A01, A10, A11, A20, A21, A30, A31; \
    ALOADP(A00, A01, 0) ALOADP(A10, A11, 1) \
    ALOADP(A20, A21, 2) ALOADP(A30, A31, 3) \
    __builtin_amdgcn_sched_barrier(0); \
    if (DOISS) { ISSUE(cn, dn) } \
    STEP(0, A00, A01) \
    STEP(1, A10, A11) \
    { \
        u16x8 A40, A41, A50, A51, A60, A61; \
        ALOADP(A40, A41, 4) ALOADP(A50, A51, 5) ALOADP(A60, A61, 6) \
        __builtin_amdgcn_sched_barrier(0); \
        STEP(2, A20, A21) \
        STEP(3, A30, A31) \
        STEP(4, A40, A41) \
        STEP(5, A50, A51) \
        STEP(6, A60, A61) \
    } }

    ISSUE(0, 0)
    __syncthreads();          // chunk 0 in LDS
    COMPUTE(0, 0, true, 1, 1)
    __syncthreads();          // chunk 1 landed; buf0 free
    COMPUTE(1, 1, true, 2, 0)
    __syncthreads();
    COMPUTE(2, 0, true, 3, 1)
    __syncthreads();
    COMPUTE(3, 1, false, 0, 0)

    // ---- store: C layout col=lane&15 (x), row=(lane>>4)*4+reg (cout) ----
    int oz = z0 + zw;
    if (oz < 46) {
#pragma unroll
        for (int yr = 0; yr < 2; ++yr) {
            int oy = y0 + 2 * yp + yr;
            if (oy >= 46) continue;
#pragma unroll
            for (int xt = 0; xt < 3; ++xt) {
                int ox = xt * 16 + ln;
                if (ox >= 46) continue;
#pragma unroll
                for (int h = 0; h < 2; ++h) {
                    f32x4 a = acc[yr][xt][h];
#pragma unroll
                    for (int r = 0; r < 4; ++r) {
                        int co = h * 16 + tq * 4 + r;
                        out[(size_t)(b * 32 + co) * 97336 + oz * 2116 + oy * 46 + ox]
                            = a[r] + bias[co];
                    }
                }
            }
        }
    }
#undef ISSUE
#undef MFMA6
#undef STEP
#undef ALOADP
#undef COMPUTE
}

// ================= fallback path (R2, proven) ============================
__global__ __launch_bounds__(64) void wnorm16_kernel(
    const float* __restrict__ s, const float* __restrict__ sw,
    const float* __restrict__ sb, const float* __restrict__ w,
    u16* __restrict__ wA)          // [b][chunk2][cout][tap28][ci16]
{
    int bc = blockIdx.x;
    int b = bc >> 5, co = bc & 31;
    int lane = threadIdx.x;
    float s0 = s[2 * b], s1 = s[2 * b + 1];

    float sum = 0.f;
    for (int i = lane; i < 864; i += 64) {
        int ci = i / 27;
        float m = fmaf(s0, sw[2 * ci], fmaf(s1, sw[2 * ci + 1], sb[ci]));
        float v = w[co * 864 + i] * m;
        sum += v * v;
    }
#pragma unroll
    for (int off = 32; off; off >>= 1) sum += __shfl_xor(sum, off, 64);
    float rn = 1.0f / sqrtf(sum + 1e-8f);

    for (int i = lane; i < 864; i += 64) {
        int ci = i / 27, tap = i - ci * 27;
        float m = fmaf(s0, sw[2 * ci], fmaf(s1, sw[2 * ci + 1], sb[ci]));
        float v = w[co * 864 + i] * m * rn;
        int chunk = ci >> 4, ci16 = ci & 15;
        wA[(((b * 2 + chunk) * 32 + co) * 28 + tap) * 16 + ci16] = f2bf(v);
    }
    if (lane < 32) {
        int c = lane >> 4, ci16 = lane & 15;
        wA[(((b * 2 + c) * 32 + co) * 28 + 27) * 16 + ci16] = 0;
    }
}

__global__ __launch_bounds__(512) void conv_fallback(
    const float* __restrict__ xin, const u16* __restrict__ wA,
    const float* __restrict__ bias, float* __restrict__ out)
{
    __shared__ u16 sx[28800];

    int blk = blockIdx.x;
    int zt = blk % 12, yt = (blk / 12) % 12, b = blk / 144;
    int z0 = zt * 4, y0 = yt * 4;

    int t = threadIdx.x;
    int l = t & 63, w = t >> 6;
    int ln = l & 15, ch = (l >> 4) & 1, tp = l >> 5, rg = l >> 4;
    int zw = w & 3, yp = w >> 2;

    f32x4 acc[2][3][2];
#pragma unroll
    for (int i = 0; i < 2; i++)
#pragma unroll
        for (int j = 0; j < 3; j++)
#pragma unroll
            for (int h = 0; h < 2; h++) acc[i][j][h] = (f32x4)0.f;

    for (int chunk = 0; chunk < 2; ++chunk) {
        __syncthreads();
        for (int idx = t; idx < 3600; idx += 512) {
            int x = idx % 50;
            int r = idx / 50;
            int cg = r & 1; r >>= 1;
            int y = r % 6, z = r / 6;
            int gz = z0 + z, gy = y0 + y;
            bool inb = (x < 48) && (gy < 48) && (gz < 48);
            const float* xp = xin + (size_t)(b * 32 + chunk * 16 + cg * 8) * 110592
                              + gz * 2304 + gy * 48 + x;
            u16x8 v;
#pragma unroll
            for (int j = 0; j < 8; j++) {
                float f = inb ? xp[(size_t)j * 110592] : 0.f;
                v[j] = f2bf(f);
            }
            *(u16x8*)&sx[idx * 8] = v;
        }
        __syncthreads();

        const u16* wAc = wA + (b * 2 + chunk) * (32 * 28 * 16);
        int aoff = (ln * 28 + tp) * 16 + ch * 8;

#pragma unroll
        for (int s = 0; s < 14; ++s) {
            int tapA = 2 * s + tp;
            bf16x8 A0 = __builtin_bit_cast(bf16x8, *(const u16x8*)(wAc + aoff + s * 32));
            bf16x8 A1 = __builtin_bit_cast(bf16x8, *(const u16x8*)(wAc + aoff + 16 * 28 * 16 + s * 32));
            int tapB = tapA > 26 ? 26 : tapA;
            int dz = tapB / 9;
            int rr = tapB - dz * 9;
            int dy = rr / 3;
            int dx = rr - dy * 3;
            int zr = zw + dz;
#pragma unroll
            for (int yr = 0; yr < 2; ++yr) {
                int yy = 2 * yp + yr + dy;
                int eb = (((zr * 6 + yy) * 2 + ch) * 50 + ln + dx) * 8;
#pragma unroll
                for (int xt = 0; xt < 3; ++xt) {
                    bf16x8 Bf = __builtin_bit_cast(bf16x8, *(const u16x8*)&sx[eb + xt * 128]);
                    acc[yr][xt][0] = __builtin_amdgcn_mfma_f32_16x16x32_bf16(A0, Bf, acc[yr][xt][0], 0, 0, 0);
                    acc[yr][xt][1] = __builtin_amdgcn_mfma_f32_16x16x32_bf16(A1, Bf, acc[yr][xt][1], 0, 0, 0);
                }
            }
        }
    }

    int oz = z0 + zw;
    if (oz < 46) {
#pragma unroll
        for (int yr = 0; yr < 2; ++yr) {
            int oy = y0 + 2 * yp + yr;
            if (oy >= 46) continue;
#pragma unroll
            for (int xt = 0; xt < 3; ++xt) {
                int ox = xt * 16 + ln;
                if (ox >= 46) continue;
#pragma unroll
                for (int h = 0; h < 2; ++h) {
                    f32x4 a = acc[yr][xt][h];
#pragma unroll
                    for (int r = 0; r < 4; ++r) {
                        int co = h * 16 + rg * 4 + r;
                        out[(size_t)(b * 32 + co) * 97336 + oz * 2116 + oy * 46 + ox]
                            = a[r] + bias[co];
                    }
                }
            }
        }
    }
}

extern "C" void kernel_launch(void* const* d_in, const int* in_sizes, int n_in,
                              void* d_out, int out_size, void* d_ws, size_t ws_size,
                              hipStream_t stream) {
    const float* x    = (const float*)d_in[0];
    const float* s    = (const float*)d_in[1];
    const float* sw   = (const float*)d_in[2];
    const float* sb   = (const float*)d_in[3];
    const float* wgt  = (const float*)d_in[4];
    const float* bias = (const float*)d_in[5];
    float* out = (float*)d_out;

    const size_t need = (size_t)XT_BYTES + WA_ELEMS * sizeof(u16);
    if (ws_size >= need) {
        u16* xT = (u16*)d_ws;
        u16* wA = (u16*)((char*)d_ws + XT_BYTES);
        hipLaunchKernelGGL(xpose_kernel, dim3(3456), dim3(256), 0, stream, x, xT);
        hipLaunchKernelGGL(wnorm8_kernel, dim3(256), dim3(64), 0, stream,
                           s, sw, sb, wgt, wA);
        hipLaunchKernelGGL(conv_dma, dim3(12 * 12 * 8), dim3(512), 0, stream,
                           xT, wA, bias, out);
    } else {
        u16* wA = (u16*)d_ws;
        hipLaunchKernelGGL(wnorm16_kernel, dim3(256), dim3(64), 0, stream,
                           s, sw, sb, wgt, wA);
        hipLaunchKernelGGL(conv_fallback, dim3(12 * 12 * 8), dim3(512), 0, stream,
                           x, wA, bias, out);
    }
}